// Round 7
// baseline (134.278 us; speedup 1.0000x reference)
//
#include <hip/hip_runtime.h>

typedef unsigned short u16;
typedef __attribute__((ext_vector_type(8))) short bf16x8;   // 8 bf16 (4 VGPRs)
typedef __attribute__((ext_vector_type(4))) float f32x4;

#define HEADS 12
#define HDIM  64
#define EMBED 768
#define TD    2304
#define SEQ   1024
#define MTOK  8192
#define GK    768
#define GNT   24   // GK / 32

// round-to-nearest-even f32 -> bf16
__device__ __forceinline__ u16 f2bf(float f) {
  union { float f; unsigned u; } x; x.f = f;
  unsigned r = x.u + 0x7fffu + ((x.u >> 16) & 1u);
  return (u16)(r >> 16);
}

// all three f32->bf16 casts in one launch
__global__ void cast3_kernel(const float* __restrict__ x, const float* __restrict__ wq,
                             const float* __restrict__ wp, u16* __restrict__ xb,
                             u16* __restrict__ wqb, u16* __restrict__ wpb) {
  const int N1 = MTOK * EMBED / 4, N2 = TD * EMBED / 4, N3 = EMBED * EMBED / 4;
  int i = blockIdx.x * blockDim.x + threadIdx.x;
  int st = gridDim.x * blockDim.x;
  for (; i < N1 + N2 + N3; i += st) {
    const float* s; u16* d; int j;
    if (i < N1)           { s = x;  d = xb;  j = i; }
    else if (i < N1 + N2) { s = wq; d = wqb; j = i - N1; }
    else                  { s = wp; d = wpb; j = i - N1 - N2; }
    float4 v = reinterpret_cast<const float4*>(s)[j];
    ushort4 o;
    o.x = f2bf(v.x); o.y = f2bf(v.y); o.z = f2bf(v.z); o.w = f2bf(v.w);
    reinterpret_cast<ushort4*>(d)[j] = o;
  }
}

__device__ __forceinline__ void gload_lds16(const u16* g, u16* l) {
  __builtin_amdgcn_global_load_lds(
      (const __attribute__((address_space(1))) unsigned*)g,
      (__attribute__((address_space(3))) unsigned*)l, 16, 0, 0);
}

__device__ __forceinline__ void memfence_bar() {
  asm volatile("" ::: "memory");
  __builtin_amdgcn_s_barrier();
  asm volatile("" ::: "memory");
}

// C[M][N] = A[M][768] @ B[N][768]^T + bias; out bf16 or f32.
// BM=128, BN=96, BK=32; 256 thr = 4 waves (2x2), wave tile 64x48.
// Ring-3 LDS on A and B (42 KB -> 3 blocks/CU). Register-pipelined fragments:
// MFMA(t) on regs loaded last iter while ds_reads(t+1) + gloads(t+3) fly.
// BK=32 frag reads are contiguous 1024B blocks -> conflict-free, no swizzle.
template <bool OUT_BF16>
__global__ __launch_bounds__(256, 3) void gemm_pipe(const u16* __restrict__ A,
                                                    const u16* __restrict__ B,
                                                    const float* __restrict__ bias,
                                                    void* __restrict__ Cv,
                                                    int NBN, int Ndim) {
  __shared__ u16 As[3][128 * 32];   // 3 x 8 KB, 8 slots of 16 rows
  __shared__ u16 Bs[3][96 * 32];    // 3 x 6 KB, 6 slots
  const int tid  = threadIdx.x;
  const int wave = tid >> 6, lane = tid & 63;
  const int wr = wave >> 1, wc = wave & 1;
  const int lr = lane & 15, g = lane >> 4;

  const int nwg = gridDim.x;
  const int swz = (blockIdx.x & 7) * (nwg >> 3) + (blockIdx.x >> 3);
  const int ny = swz % NBN, mx = swz / NBN;

  const u16* Ag = A + (size_t)(mx * 128) * GK;
  const u16* Bg = B + (size_t)(ny * 96) * GK;

  const int srow = lane >> 2;        // row within 16-row slot
  const int scol = (lane & 3) * 8;   // element offset (16B chunk)

  // per-wave gloads/tile: waves 0,1 -> 4 (2A+2B); waves 2,3 -> 3 (2A+1B)
  auto stage = [&](int kt) {
    const int buf = kt % 3;
    const int k0 = kt * 32;
#pragma unroll
    for (int c = 0; c < 2; ++c) {
      int slot = wave * 2 + c;                 // 0..7
      int row  = slot * 16 + srow;
      gload_lds16(Ag + (size_t)row * GK + k0 + scol, &As[buf][slot * 512]);
    }
    if (wave < 2) {
#pragma unroll
      for (int c = 0; c < 2; ++c) {
        int slot = wave * 2 + c;               // 0..3
        int row  = slot * 16 + srow;
        gload_lds16(Bg + (size_t)row * GK + k0 + scol, &Bs[buf][slot * 512]);
      }
    } else {
      int slot = wave + 2;                     // 4,5
      int row  = slot * 16 + srow;
      gload_lds16(Bg + (size_t)row * GK + k0 + scol, &Bs[buf][slot * 512]);
    }
  };
  auto vmwait2 = [&] {  // 2 tiles in flight
    if (wave < 2) asm volatile("s_waitcnt vmcnt(8)" ::: "memory");
    else          asm volatile("s_waitcnt vmcnt(6)" ::: "memory");
  };
  auto vmwait1 = [&] {  // 1 tile in flight
    if (wave < 2) asm volatile("s_waitcnt vmcnt(4)" ::: "memory");
    else          asm volatile("s_waitcnt vmcnt(3)" ::: "memory");
  };

  f32x4 acc[4][3];
#pragma unroll
  for (int m = 0; m < 4; ++m)
#pragma unroll
    for (int n = 0; n < 3; ++n) acc[m][n] = 0.f;

  auto readfr = [&](int u, bf16x8* af, bf16x8* bf) {
    const int buf = u % 3;
#pragma unroll
    for (int m = 0; m < 4; ++m)
      af[m] = *reinterpret_cast<const bf16x8*>(&As[buf][(wr * 64 + m * 16 + lr) * 32 + g * 8]);
#pragma unroll
    for (int n = 0; n < 3; ++n)
      bf[n] = *reinterpret_cast<const bf16x8*>(&Bs[buf][(wc * 48 + n * 16 + lr) * 32 + g * 8]);
  };
  auto domfma = [&](const bf16x8* af, const bf16x8* bf) {
    __builtin_amdgcn_s_setprio(1);
#pragma unroll
    for (int m = 0; m < 4; ++m)
#pragma unroll
      for (int n = 0; n < 3; ++n)
        acc[m][n] = __builtin_amdgcn_mfma_f32_16x16x32_bf16(bf[n], af[m], acc[m][n], 0, 0, 0);
    __builtin_amdgcn_s_setprio(0);
  };
  // half-iteration for tile u: finish frags(u), allow overwrite of slot u%3,
  // stage(u+3), ensure tile u+1 landed, issue reads(u+1), MFMA(u).
  auto halfiter = [&](int u, const bf16x8* afc, const bf16x8* bfc,
                      bf16x8* afn, bf16x8* bfn) {
    asm volatile("s_waitcnt lgkmcnt(0)" ::: "memory");
    memfence_bar();
    if (u + 3 < GNT) stage(u + 3);
    if (u + 3 < GNT)      vmwait2();
    else if (u + 3 == GNT) vmwait1();
    else if (u + 2 == GNT) asm volatile("s_waitcnt vmcnt(0)" ::: "memory");
    if (u + 1 < GNT) readfr(u + 1, afn, bfn);
    domfma(afc, bfc);
  };

  bf16x8 af0[4], bf0[3], af1[4], bf1[3];

  stage(0); stage(1); stage(2);
  vmwait2();
  memfence_bar();
  readfr(0, af0, bf0);

  for (int t = 0; t < GNT; t += 2) {
    halfiter(t,     af0, bf0, af1, bf1);
    halfiter(t + 1, af1, bf1, af0, bf0);
  }

  const int row0 = mx * 128 + wr * 64 + lr;
  const int col0 = ny * 96 + wc * 48 + g * 4;
#pragma unroll
  for (int m = 0; m < 4; ++m)
#pragma unroll
    for (int n = 0; n < 3; ++n) {
      int row = row0 + m * 16;
      int col = col0 + n * 16;
      float4 bv = *reinterpret_cast<const float4*>(&bias[col]);
      float v0 = acc[m][n][0] + bv.x, v1 = acc[m][n][1] + bv.y;
      float v2 = acc[m][n][2] + bv.z, v3 = acc[m][n][3] + bv.w;
      if (OUT_BF16) {
        ushort4 pw;
        pw.x = f2bf(v0); pw.y = f2bf(v1); pw.z = f2bf(v2); pw.w = f2bf(v3);
        *reinterpret_cast<ushort4*>(&((u16*)Cv)[(size_t)row * Ndim + col]) = pw;
      } else {
        *reinterpret_cast<float4*>(&((float*)Cv)[(size_t)row * Ndim + col]) =
            make_float4(v0, v1, v2, v3);
      }
    }
}

// Transpose V region of qkv into vt[bh][e][tok] (bf16).
__global__ __launch_bounds__(256) void vtrans_kernel(const u16* __restrict__ qkv,
                                                     u16* __restrict__ vt) {
  const int bh = blockIdx.x, kb = blockIdx.y;
  const int b = bh / HEADS, h = bh % HEADS;
  __shared__ u16 Ls[64 * 72];
  const int t = threadIdx.x;
  const int row = t >> 2, seg = t & 3;
  const u16* src = qkv + (size_t)(b * SEQ + kb * 64 + row) * TD + 2 * EMBED + h * HDIM + seg * 16;
  *reinterpret_cast<uint4*>(&Ls[row * 72 + seg * 16])     = *reinterpret_cast<const uint4*>(src);
  *reinterpret_cast<uint4*>(&Ls[row * 72 + seg * 16 + 8]) = *reinterpret_cast<const uint4*>(src + 8);
  __syncthreads();
  u16 tmp[16];
#pragma unroll
  for (int i = 0; i < 16; ++i) tmp[i] = Ls[(seg * 16 + i) * 72 + row];
  u16* dst = vt + (size_t)bh * (HDIM * SEQ) + (size_t)row * SEQ + kb * 64 + seg * 16;
  *reinterpret_cast<uint4*>(dst)     = *reinterpret_cast<const uint4*>(tmp);
  *reinterpret_cast<uint4*>(dst + 8) = *reinterpret_cast<const uint4*>(tmp + 8);
}

// Fused attention: block = (bh, 128-row Q tile), 4 waves. K/V double-buffered,
// raw barriers + end-of-tile vmcnt(0). Swapped QK^T; wave-private P.
// V-fragments (vb2) are read BEFORE the QK cluster so they prefetch under it.
__global__ __launch_bounds__(256, 3) void attn_kernel(const u16* __restrict__ qkv,
                                                      const u16* __restrict__ vt,
                                                      u16* __restrict__ ctx) {
  const int bh = blockIdx.x;
  const int b = bh / HEADS, h = bh % HEADS;
  const int qt = blockIdx.y;
  const int tid = threadIdx.x, wave = tid >> 6, lane = tid & 63;
  const int lr = lane & 15, g = lane >> 4;

  __shared__ u16 Ks[2][64 * 64];  // [k-row][d], swizzled chunks
  __shared__ u16 Vs[2][64 * 64];  // [e][k] (pre-transposed), same swizzle
  __shared__ u16 Ps[128 * 64];    // [m][k], 8B granules swizzled

  const size_t tok0 = (size_t)b * SEQ;
  const int q0 = qt * 128;
  const int mbase = wave * 32;

  bf16x8 qf[2][2];
#pragma unroll
  for (int mi = 0; mi < 2; ++mi)
#pragma unroll
    for (int dk = 0; dk < 2; ++dk)
      qf[mi][dk] = *reinterpret_cast<const bf16x8*>(
          qkv + (tok0 + q0 + mbase + mi * 16 + lr) * TD + h * HDIM + dk * 32 + g * 8);

  const int srow = lane >> 3;
  const int schunk = (lane & 7) ^ srow;
  const u16* vbase = vt + (size_t)bh * (HDIM * SEQ);

  auto stage = [&](int kb, int buf) {       // 4 gloads/thread
#pragma unroll
    for (int c2 = 0; c2 < 2; ++c2) {
      int call = wave * 2 + c2;
      int row  = call * 8 + srow;
      gload_lds16(qkv + (tok0 + kb * 64 + row) * TD + EMBED + h * HDIM + schunk * 8,
                  &Ks[buf][call * 512]);
      gload_lds16(vbase + (size_t)row * SEQ + kb * 64 + schunk * 8,
                  &Vs[buf][call * 512]);
    }
  };

  f32x4 oacc[2][4];
#pragma unroll
  for (int mi = 0; mi < 2; ++mi)
#pragma unroll
    for (int e = 0; e < 4; ++e) oacc[mi][e] = 0.f;
  float psum[2] = {0.f, 0.f};

  stage(0, 0);
  asm volatile("s_waitcnt vmcnt(0)" ::: "memory");
  memfence_bar();

  int cur = 0;
  for (int kb = 0; kb < 16; ++kb) {
    if (kb < 15) stage(kb + 1, cur ^ 1);

    // K and V fragment reads issued together; V prefetches under QK+exp.
    bf16x8 ka[4][2], vb2[4][2];
#pragma unroll
    for (int n = 0; n < 4; ++n)
#pragma unroll
      for (int dk = 0; dk < 2; ++dk) {
        int r = n * 16 + lr;
        int c = dk * 4 + g;
        ka[n][dk]  = *reinterpret_cast<const bf16x8*>(&Ks[cur][r * 64 + ((c ^ (r & 7)) << 3)]);
        vb2[n][dk] = *reinterpret_cast<const bf16x8*>(&Vs[cur][r * 64 + ((c ^ (r & 7)) << 3)]);
      }

    // S^T = K @ Q^T, then P = exp(S), bf16, to wave-private LDS
#pragma unroll
    for (int mi = 0; mi < 2; ++mi) {
      int m = mbase + mi * 16 + lr;
      int pswz = (lr & 7) << 1;
#pragma unroll
      for (int n = 0; n < 4; ++n) {
        f32x4 s = 0.f;
        __builtin_amdgcn_s_setprio(1);
        s = __builtin_amdgcn_mfma_f32_16x16x32_bf16(ka[n][0], qf[mi][0], s, 0, 0, 0);
        s = __builtin_amdgcn_mfma_f32_16x16x32_bf16(ka[n][1], qf[mi][1], s, 0, 0, 0);
        __builtin_amdgcn_s_setprio(0);
        float e0 = __expf(s[0]), e1 = __expf(s[1]);
        float e2 = __expf(s[2]), e3 = __expf(s[3]);
        psum[mi] += (e0 + e1) + (e2 + e3);
        ushort4 pw;
        pw.x = f2bf(e0); pw.y = f2bf(e1); pw.z = f2bf(e2); pw.w = f2bf(e3);
        int gran = n * 4 + g;
        *reinterpret_cast<ushort4*>(&Ps[m * 64 + ((gran ^ pswz) << 2)]) = pw;
      }
    }

    // O += P @ V (P wave-private)
#pragma unroll
    for (int mi = 0; mi < 2; ++mi) {
      bf16x8 pa[2];
#pragma unroll
      for (int kk = 0; kk < 2; ++kk) {
        int r = mbase + mi * 16 + lr;
        int c = kk * 4 + g;
        pa[kk] = *reinterpret_cast<const bf16x8*>(&Ps[r * 64 + ((c ^ (r & 7)) << 3)]);
      }
      __builtin_amdgcn_s_setprio(1);
#pragma unroll
      for (int e = 0; e < 4; ++e) {
        oacc[mi][e] = __builtin_amdgcn_mfma_f32_16x16x32_bf16(pa[0], vb2[e][0], oacc[mi][e], 0, 0, 0);
        oacc[mi][e] = __builtin_amdgcn_mfma_f32_16x16x32_bf16(pa[1], vb2[e][1], oacc[mi][e], 0, 0, 0);
      }
      __builtin_amdgcn_s_setprio(0);
    }

    if (kb < 15) {
      asm volatile("s_waitcnt vmcnt(0)" ::: "memory");  // next K/V staged
      memfence_bar();
    }
    cur ^= 1;
  }

  float scl[2][4];
#pragma unroll
  for (int mi = 0; mi < 2; ++mi) {
    float v = psum[mi];
    v += __shfl_xor(v, 16);
    v += __shfl_xor(v, 32);
    v = 0.125f / v;
#pragma unroll
    for (int j = 0; j < 4; ++j) scl[mi][j] = __shfl(v, 4 * g + j);
  }
#pragma unroll
  for (int mi = 0; mi < 2; ++mi)
#pragma unroll
    for (int e = 0; e < 4; ++e)
#pragma unroll
      for (int j = 0; j < 4; ++j) {
        float v = oacc[mi][e][j] * scl[mi][j];
        ctx[(tok0 + q0 + mbase + mi * 16 + 4 * g + j) * EMBED + h * HDIM + e * 16 + lr] = f2bf(v);
      }
}

extern "C" void kernel_launch(void* const* d_in, const int* in_sizes, int n_in,
                              void* d_out, int out_size, void* d_ws, size_t ws_size,
                              hipStream_t stream) {
  (void)in_sizes; (void)n_in; (void)out_size;
  const float* x     = (const float*)d_in[0];
  const float* Wqkv  = (const float*)d_in[1];
  const float* bqkv  = (const float*)d_in[2];
  const float* Wproj = (const float*)d_in[3];
  const float* bproj = (const float*)d_in[4];
  float* out = (float*)d_out;

  char* ws = (char*)d_ws;
  size_t off = 0;
  auto alloc = [&](size_t bytes) {
    char* p = ws + off;
    off += (bytes + 255) & ~(size_t)255;
    return p;
  };
  u16* xb     = (u16*)alloc((size_t)MTOK * EMBED * 2);
  u16* wqkvb  = (u16*)alloc((size_t)TD * EMBED * 2);
  u16* wprojb = (u16*)alloc((size_t)EMBED * EMBED * 2);
  u16* qkvb   = (u16*)alloc((size_t)MTOK * TD * 2);
  u16* ctxb   = (u16*)alloc((size_t)MTOK * EMBED * 2);
  if (off > ws_size) return;  // workspace too small: loud failure
  u16* vtb = xb;  // reuse: xb is dead after the QKV GEMM; vt is same size

  cast3_kernel<<<dim3(2048), dim3(256), 0, stream>>>(x, Wqkv, Wproj, xb, wqkvb, wprojb);

  // QKV projection: grid 64x24 = 1536 blocks = 2.0 rounds @ 3 blocks/CU
  gemm_pipe<true><<<dim3(1536), dim3(256), 0, stream>>>(xb, wqkvb, bqkv, qkvb, 24, TD);
  // V transpose into vt[bh][e][tok] (aliases xb)
  vtrans_kernel<<<dim3(96, 16), dim3(256), 0, stream>>>(qkvb, vtb);
  // fused attention
  attn_kernel<<<dim3(96, 8), dim3(256), 0, stream>>>(qkvb, vtb, ctxb);
  // output projection: grid 64x8 = 512 blocks, single round
  gemm_pipe<false><<<dim3(512), dim3(256), 0, stream>>>(ctxb, wprojb, bproj, out, 8, EMBED);
}

// Round 8
// 125.004 us; speedup vs baseline: 1.0742x; 1.0742x over previous
//
#include <hip/hip_runtime.h>

typedef unsigned short u16;
typedef __attribute__((ext_vector_type(8))) short bf16x8;   // 8 bf16 (4 VGPRs)
typedef __attribute__((ext_vector_type(4))) float f32x4;

#define HEADS 12
#define HDIM  64
#define EMBED 768
#define TD    2304
#define SEQ   1024
#define MTOK  8192
#define GK    768
#define GNT   12   // GK / 64

// round-to-nearest-even f32 -> bf16
__device__ __forceinline__ u16 f2bf(float f) {
  union { float f; unsigned u; } x; x.f = f;
  unsigned r = x.u + 0x7fffu + ((x.u >> 16) & 1u);
  return (u16)(r >> 16);
}

// all three f32->bf16 casts in one launch
__global__ void cast3_kernel(const float* __restrict__ x, const float* __restrict__ wq,
                             const float* __restrict__ wp, u16* __restrict__ xb,
                             u16* __restrict__ wqb, u16* __restrict__ wpb) {
  const int N1 = MTOK * EMBED / 4, N2 = TD * EMBED / 4, N3 = EMBED * EMBED / 4;
  int i = blockIdx.x * blockDim.x + threadIdx.x;
  int st = gridDim.x * blockDim.x;
  for (; i < N1 + N2 + N3; i += st) {
    const float* s; u16* d; int j;
    if (i < N1)           { s = x;  d = xb;  j = i; }
    else if (i < N1 + N2) { s = wq; d = wqb; j = i - N1; }
    else                  { s = wp; d = wpb; j = i - N1 - N2; }
    float4 v = reinterpret_cast<const float4*>(s)[j];
    ushort4 o;
    o.x = f2bf(v.x); o.y = f2bf(v.y); o.z = f2bf(v.z); o.w = f2bf(v.w);
    reinterpret_cast<ushort4*>(d)[j] = o;
  }
}

__device__ __forceinline__ void gload_lds16(const u16* g, u16* l) {
  __builtin_amdgcn_global_load_lds(
      (const __attribute__((address_space(1))) unsigned*)g,
      (__attribute__((address_space(3))) unsigned*)l, 16, 0, 0);
}

__device__ __forceinline__ void memfence_bar() {
  asm volatile("" ::: "memory");
  __builtin_amdgcn_s_barrier();
  asm volatile("" ::: "memory");
}

// C[M][N] = A[M][768] @ B[N][768]^T + bias; out bf16 or f32.
// BM=128, BN=96, BK=64; 256 thr = 4 waves (2x2), wave tile 64x48.
// A ring-3 + B dbuf (72 KB -> 2 blocks/CU). Minimum-2-phase schedule:
// stage-issue first, ds_reads, MFMA (compiler-interleaved waits, no fences),
// counted vmcnt(4), ONE barrier per K-tile. XOR-swizzled tiles (conflict-free
// at 128B row stride: bank = 4*(c^(r&7)), 2-way max).
template <bool OUT_BF16>
__global__ __launch_bounds__(256, 2) void gemm_min2(const u16* __restrict__ A,
                                                    const u16* __restrict__ B,
                                                    const float* __restrict__ bias,
                                                    void* __restrict__ Cv,
                                                    int NBN, int Ndim) {
  __shared__ u16 As[3][128 * 64];   // 3 x 16 KB, buf = t % 3
  __shared__ u16 Bs[2][96 * 64];    // 2 x 12 KB, buf = t & 1
  const int tid  = threadIdx.x;
  const int wave = tid >> 6, lane = tid & 63;
  const int wr = wave >> 1, wc = wave & 1;
  const int lr = lane & 15, g = lane >> 4;

  const int nwg = gridDim.x;
  const int swz = (blockIdx.x & 7) * (nwg >> 3) + (blockIdx.x >> 3);
  const int ny = swz % NBN, mx = swz / NBN;

  const u16* Ag = A + (size_t)(mx * 128) * GK;
  const u16* Bg = B + (size_t)(ny * 96) * GK;

  const int srow   = lane >> 3;             // row within 8-row slot
  const int schunk = (lane & 7) ^ srow;     // pre-swizzled source 16B-chunk

  auto stageA = [&](int kt) {               // 4 gloads/thread, buf kt%3
    u16* dst = As[kt % 3];
#pragma unroll
    for (int c = 0; c < 4; ++c) {
      int slot = wave * 4 + c;              // 0..15
      int row  = slot * 8 + srow;
      gload_lds16(Ag + (size_t)row * GK + kt * 64 + schunk * 8, &dst[slot * 512]);
    }
  };
  auto stageB = [&](int kt) {               // 3 gloads/thread, buf kt&1
    u16* dst = Bs[kt & 1];
#pragma unroll
    for (int c = 0; c < 3; ++c) {
      int slot = wave * 3 + c;              // 0..11
      int row  = slot * 8 + srow;
      gload_lds16(Bg + (size_t)row * GK + kt * 64 + schunk * 8, &dst[slot * 512]);
    }
  };

  f32x4 acc[4][3];
#pragma unroll
  for (int m = 0; m < 4; ++m)
#pragma unroll
    for (int n = 0; n < 3; ++n) acc[m][n] = 0.f;

  // prologue: A(0),B(0),A(1); wait all but the newest 4 (A(1) in flight)
  stageA(0);
  stageB(0);
  stageA(1);
  asm volatile("s_waitcnt vmcnt(4)" ::: "memory");
  memfence_bar();

  for (int t = 0; t < GNT; ++t) {
    // issue next stages FIRST (targets are tile t-1 slots, reads done last iter)
    if (t + 1 < GNT) stageB(t + 1);
    if (t + 2 < GNT) stageA(t + 2);

    // fragment reads from current buffers; NO explicit drain — the compiler
    // interleaves lgkmcnt(N) with the MFMA cluster.
    const u16* Ab = As[t % 3];
    const u16* Bb = Bs[t & 1];
    bf16x8 af[4][2], bfr[3][2];
#pragma unroll
    for (int m = 0; m < 4; ++m)
#pragma unroll
      for (int kk = 0; kk < 2; ++kk) {
        int r = wr * 64 + m * 16 + lr;
        af[m][kk] = *reinterpret_cast<const bf16x8*>(
            &Ab[r * 64 + (((kk * 4 + g) ^ (r & 7)) << 3)]);
      }
#pragma unroll
    for (int n = 0; n < 3; ++n)
#pragma unroll
      for (int kk = 0; kk < 2; ++kk) {
        int r = wc * 48 + n * 16 + lr;
        bfr[n][kk] = *reinterpret_cast<const bf16x8*>(
            &Bb[r * 64 + (((kk * 4 + g) ^ (r & 7)) << 3)]);
      }

    __builtin_amdgcn_s_setprio(1);
#pragma unroll
    for (int m = 0; m < 4; ++m)
#pragma unroll
      for (int n = 0; n < 3; ++n) {
        acc[m][n] = __builtin_amdgcn_mfma_f32_16x16x32_bf16(bfr[n][0], af[m][0], acc[m][n], 0, 0, 0);
        acc[m][n] = __builtin_amdgcn_mfma_f32_16x16x32_bf16(bfr[n][1], af[m][1], acc[m][n], 0, 0, 0);
      }
    __builtin_amdgcn_s_setprio(0);

    // counted drain once per tile: tile t+1 fully staged; A(t+2) in flight
    if (t + 3 <= GNT) {
      asm volatile("s_waitcnt vmcnt(4)" ::: "memory");
      memfence_bar();
    } else if (t + 2 == GNT) {
      asm volatile("s_waitcnt vmcnt(0)" ::: "memory");
      memfence_bar();
    }
  }

  const int row0 = mx * 128 + wr * 64 + lr;
  const int col0 = ny * 96 + wc * 48 + g * 4;
#pragma unroll
  for (int m = 0; m < 4; ++m)
#pragma unroll
    for (int n = 0; n < 3; ++n) {
      int row = row0 + m * 16;
      int col = col0 + n * 16;
      float4 bv = *reinterpret_cast<const float4*>(&bias[col]);
      float v0 = acc[m][n][0] + bv.x, v1 = acc[m][n][1] + bv.y;
      float v2 = acc[m][n][2] + bv.z, v3 = acc[m][n][3] + bv.w;
      if (OUT_BF16) {
        ushort4 pw;
        pw.x = f2bf(v0); pw.y = f2bf(v1); pw.z = f2bf(v2); pw.w = f2bf(v3);
        *reinterpret_cast<ushort4*>(&((u16*)Cv)[(size_t)row * Ndim + col]) = pw;
      } else {
        *reinterpret_cast<float4*>(&((float*)Cv)[(size_t)row * Ndim + col]) =
            make_float4(v0, v1, v2, v3);
      }
    }
}

// Transpose V region of qkv into vt[bh][e][tok] (bf16).
__global__ __launch_bounds__(256) void vtrans_kernel(const u16* __restrict__ qkv,
                                                     u16* __restrict__ vt) {
  const int bh = blockIdx.x, kb = blockIdx.y;
  const int b = bh / HEADS, h = bh % HEADS;
  __shared__ u16 Ls[64 * 72];
  const int t = threadIdx.x;
  const int row = t >> 2, seg = t & 3;
  const u16* src = qkv + (size_t)(b * SEQ + kb * 64 + row) * TD + 2 * EMBED + h * HDIM + seg * 16;
  *reinterpret_cast<uint4*>(&Ls[row * 72 + seg * 16])     = *reinterpret_cast<const uint4*>(src);
  *reinterpret_cast<uint4*>(&Ls[row * 72 + seg * 16 + 8]) = *reinterpret_cast<const uint4*>(src + 8);
  __syncthreads();
  u16 tmp[16];
#pragma unroll
  for (int i = 0; i < 16; ++i) tmp[i] = Ls[(seg * 16 + i) * 72 + row];
  u16* dst = vt + (size_t)bh * (HDIM * SEQ) + (size_t)row * SEQ + kb * 64 + seg * 16;
  *reinterpret_cast<uint4*>(dst)     = *reinterpret_cast<const uint4*>(tmp);
  *reinterpret_cast<uint4*>(dst + 8) = *reinterpret_cast<const uint4*>(tmp + 8);
}

// Fused attention: block = (bh, 128-row Q tile), 4 waves. K/V double-buffered,
// raw barriers + end-of-tile vmcnt(0). Swapped QK^T; wave-private P.
// V-fragments (vb2) are read BEFORE the QK cluster so they prefetch under it.
__global__ __launch_bounds__(256, 3) void attn_kernel(const u16* __restrict__ qkv,
                                                      const u16* __restrict__ vt,
                                                      u16* __restrict__ ctx) {
  const int bh = blockIdx.x;
  const int b = bh / HEADS, h = bh % HEADS;
  const int qt = blockIdx.y;
  const int tid = threadIdx.x, wave = tid >> 6, lane = tid & 63;
  const int lr = lane & 15, g = lane >> 4;

  __shared__ u16 Ks[2][64 * 64];  // [k-row][d], swizzled chunks
  __shared__ u16 Vs[2][64 * 64];  // [e][k] (pre-transposed), same swizzle
  __shared__ u16 Ps[128 * 64];    // [m][k], 8B granules swizzled

  const size_t tok0 = (size_t)b * SEQ;
  const int q0 = qt * 128;
  const int mbase = wave * 32;

  bf16x8 qf[2][2];
#pragma unroll
  for (int mi = 0; mi < 2; ++mi)
#pragma unroll
    for (int dk = 0; dk < 2; ++dk)
      qf[mi][dk] = *reinterpret_cast<const bf16x8*>(
          qkv + (tok0 + q0 + mbase + mi * 16 + lr) * TD + h * HDIM + dk * 32 + g * 8);

  const int srow = lane >> 3;
  const int schunk = (lane & 7) ^ srow;
  const u16* vbase = vt + (size_t)bh * (HDIM * SEQ);

  auto stage = [&](int kb, int buf) {       // 4 gloads/thread
#pragma unroll
    for (int c2 = 0; c2 < 2; ++c2) {
      int call = wave * 2 + c2;
      int row  = call * 8 + srow;
      gload_lds16(qkv + (tok0 + kb * 64 + row) * TD + EMBED + h * HDIM + schunk * 8,
                  &Ks[buf][call * 512]);
      gload_lds16(vbase + (size_t)row * SEQ + kb * 64 + schunk * 8,
                  &Vs[buf][call * 512]);
    }
  };

  f32x4 oacc[2][4];
#pragma unroll
  for (int mi = 0; mi < 2; ++mi)
#pragma unroll
    for (int e = 0; e < 4; ++e) oacc[mi][e] = 0.f;
  float psum[2] = {0.f, 0.f};

  stage(0, 0);
  asm volatile("s_waitcnt vmcnt(0)" ::: "memory");
  memfence_bar();

  int cur = 0;
  for (int kb = 0; kb < 16; ++kb) {
    if (kb < 15) stage(kb + 1, cur ^ 1);

    // K and V fragment reads issued together; V prefetches under QK+exp.
    bf16x8 ka[4][2], vb2[4][2];
#pragma unroll
    for (int n = 0; n < 4; ++n)
#pragma unroll
      for (int dk = 0; dk < 2; ++dk) {
        int r = n * 16 + lr;
        int c = dk * 4 + g;
        ka[n][dk]  = *reinterpret_cast<const bf16x8*>(&Ks[cur][r * 64 + ((c ^ (r & 7)) << 3)]);
        vb2[n][dk] = *reinterpret_cast<const bf16x8*>(&Vs[cur][r * 64 + ((c ^ (r & 7)) << 3)]);
      }

    // S^T = K @ Q^T, then P = exp(S), bf16, to wave-private LDS
#pragma unroll
    for (int mi = 0; mi < 2; ++mi) {
      int m = mbase + mi * 16 + lr;
      int pswz = (lr & 7) << 1;
#pragma unroll
      for (int n = 0; n < 4; ++n) {
        f32x4 s = 0.f;
        __builtin_amdgcn_s_setprio(1);
        s = __builtin_amdgcn_mfma_f32_16x16x32_bf16(ka[n][0], qf[mi][0], s, 0, 0, 0);
        s = __builtin_amdgcn_mfma_f32_16x16x32_bf16(ka[n][1], qf[mi][1], s, 0, 0, 0);
        __builtin_amdgcn_s_setprio(0);
        float e0 = __expf(s[0]), e1 = __expf(s[1]);
        float e2 = __expf(s[2]), e3 = __expf(s[3]);
        psum[mi] += (e0 + e1) + (e2 + e3);
        ushort4 pw;
        pw.x = f2bf(e0); pw.y = f2bf(e1); pw.z = f2bf(e2); pw.w = f2bf(e3);
        int gran = n * 4 + g;
        *reinterpret_cast<ushort4*>(&Ps[m * 64 + ((gran ^ pswz) << 2)]) = pw;
      }
    }

    // O += P @ V (P wave-private)
#pragma unroll
    for (int mi = 0; mi < 2; ++mi) {
      bf16x8 pa[2];
#pragma unroll
      for (int kk = 0; kk < 2; ++kk) {
        int r = mbase + mi * 16 + lr;
        int c = kk * 4 + g;
        pa[kk] = *reinterpret_cast<const bf16x8*>(&Ps[r * 64 + ((c ^ (r & 7)) << 3)]);
      }
      __builtin_amdgcn_s_setprio(1);
#pragma unroll
      for (int e = 0; e < 4; ++e) {
        oacc[mi][e] = __builtin_amdgcn_mfma_f32_16x16x32_bf16(pa[0], vb2[e][0], oacc[mi][e], 0, 0, 0);
        oacc[mi][e] = __builtin_amdgcn_mfma_f32_16x16x32_bf16(pa[1], vb2[e][1], oacc[mi][e], 0, 0, 0);
      }
      __builtin_amdgcn_s_setprio(0);
    }

    if (kb < 15) {
      asm volatile("s_waitcnt vmcnt(0)" ::: "memory");  // next K/V staged
      memfence_bar();
    }
    cur ^= 1;
  }

  float scl[2][4];
#pragma unroll
  for (int mi = 0; mi < 2; ++mi) {
    float v = psum[mi];
    v += __shfl_xor(v, 16);
    v += __shfl_xor(v, 32);
    v = 0.125f / v;
#pragma unroll
    for (int j = 0; j < 4; ++j) scl[mi][j] = __shfl(v, 4 * g + j);
  }
#pragma unroll
  for (int mi = 0; mi < 2; ++mi)
#pragma unroll
    for (int e = 0; e < 4; ++e)
#pragma unroll
      for (int j = 0; j < 4; ++j) {
        float v = oacc[mi][e][j] * scl[mi][j];
        ctx[(tok0 + q0 + mbase + mi * 16 + 4 * g + j) * EMBED + h * HDIM + e * 16 + lr] = f2bf(v);
      }
}

extern "C" void kernel_launch(void* const* d_in, const int* in_sizes, int n_in,
                              void* d_out, int out_size, void* d_ws, size_t ws_size,
                              hipStream_t stream) {
  (void)in_sizes; (void)n_in; (void)out_size;
  const float* x     = (const float*)d_in[0];
  const float* Wqkv  = (const float*)d_in[1];
  const float* bqkv  = (const float*)d_in[2];
  const float* Wproj = (const float*)d_in[3];
  const float* bproj = (const float*)d_in[4];
  float* out = (float*)d_out;

  char* ws = (char*)d_ws;
  size_t off = 0;
  auto alloc = [&](size_t bytes) {
    char* p = ws + off;
    off += (bytes + 255) & ~(size_t)255;
    return p;
  };
  u16* xb     = (u16*)alloc((size_t)MTOK * EMBED * 2);
  u16* wqkvb  = (u16*)alloc((size_t)TD * EMBED * 2);
  u16* wprojb = (u16*)alloc((size_t)EMBED * EMBED * 2);
  u16* qkvb   = (u16*)alloc((size_t)MTOK * TD * 2);
  u16* ctxb   = (u16*)alloc((size_t)MTOK * EMBED * 2);
  if (off > ws_size) return;  // workspace too small: loud failure
  u16* vtb = xb;  // reuse: xb is dead after the QKV GEMM; vt is same size

  cast3_kernel<<<dim3(2048), dim3(256), 0, stream>>>(x, Wqkv, Wproj, xb, wqkvb, wprojb);

  // QKV projection: grid 64x24 = 1536 blocks = 3.0 rounds @ 2 blocks/CU
  gemm_min2<true><<<dim3(1536), dim3(256), 0, stream>>>(xb, wqkvb, bqkv, qkvb, 24, TD);
  // V transpose into vt[bh][e][tok] (aliases xb)
  vtrans_kernel<<<dim3(96, 16), dim3(256), 0, stream>>>(qkvb, vtb);
  // fused attention
  attn_kernel<<<dim3(96, 8), dim3(256), 0, stream>>>(qkvb, vtb, ctxb);
  // output projection: grid 64x8 = 512 blocks = 1.0 round @ 2 blocks/CU
  gemm_min2<false><<<dim3(512), dim3(256), 0, stream>>>(ctxb, wprojb, bproj, out, 8, EMBED);
}